// Round 1
// baseline (60.960 us; speedup 1.0000x reference)
//
#include <hip/hip_runtime.h>
#include <math.h>

// ---------------------------------------------------------------------------
// MyGaussianModel: bind 2M gaussians to 9976 triangle faces.
// Phase 1: per-face frame/quat/scale precompute into d_ws (798 KB).
// Phase 2: per-gaussian transform + activation, write 14 f32 per gaussian.
// ---------------------------------------------------------------------------

struct F3 { float x, y, z; };
__device__ __forceinline__ F3 mkf3(float x, float y, float z) { F3 r; r.x = x; r.y = y; r.z = z; return r; }
__device__ __forceinline__ F3 f3sub(F3 a, F3 b) { return mkf3(a.x - b.x, a.y - b.y, a.z - b.z); }
__device__ __forceinline__ F3 f3add(F3 a, F3 b) { return mkf3(a.x + b.x, a.y + b.y, a.z + b.z); }
__device__ __forceinline__ F3 f3scl(F3 a, float s) { return mkf3(a.x * s, a.y * s, a.z * s); }
__device__ __forceinline__ float f3dot(F3 a, F3 b) { return a.x * b.x + a.y * b.y + a.z * b.z; }
__device__ __forceinline__ F3 f3cross(F3 a, F3 b) {
    return mkf3(a.y * b.z - a.z * b.y, a.z * b.x - a.x * b.z, a.x * b.y - a.y * b.x);
}

// Per-face geometry exactly following the reference semantics.
__device__ void face_geom(const float* __restrict__ verts, const int* __restrict__ faces, int f,
                          F3& a0, F3& a1, F3& a2, F3& ctr, float& fs, float4& quat_wxyz)
{
    int i0 = faces[3 * f + 0], i1 = faces[3 * f + 1], i2 = faces[3 * f + 2];
    F3 v0 = mkf3(verts[3 * i0], verts[3 * i0 + 1], verts[3 * i0 + 2]);
    F3 v1 = mkf3(verts[3 * i1], verts[3 * i1 + 1], verts[3 * i1 + 2]);
    F3 v2 = mkf3(verts[3 * i2], verts[3 * i2 + 1], verts[3 * i2 + 2]);

    ctr = f3scl(f3add(f3add(v0, v1), v2), (1.0f / 3.0f));

    F3 e1 = f3sub(v1, v0);
    float d1 = f3dot(e1, e1);
    float s0 = sqrtf(d1);
    a0 = f3scl(e1, 1.0f / sqrtf(fmaxf(d1, 1e-20f)));

    F3 e2 = f3sub(v2, v0);
    F3 c = f3cross(a0, e2);
    float dc = f3dot(c, c);
    a1 = f3scl(c, 1.0f / sqrtf(fmaxf(dc, 1e-20f)));

    F3 c2 = f3cross(a1, a0);
    float dc2 = f3dot(c2, c2);
    F3 n2 = f3scl(c2, 1.0f / sqrtf(fmaxf(dc2, 1e-20f)));
    a2 = mkf3(-n2.x, -n2.y, -n2.z);

    float s1 = fabsf(f3dot(c, a1));
    fs = 0.5f * (s0 + s1);

    // R columns are a0,a1,a2: R[i][0]=a0[i], R[i][1]=a1[i], R[i][2]=a2[i]
    float r00 = a0.x, r10 = a0.y, r20 = a0.z;
    float r01 = a1.x, r11 = a1.y, r21 = a1.z;
    float r02 = a2.x, r12 = a2.y, r22 = a2.z;
    float t = r00 + r11 + r22;

    float cand[4][4] = {
        { 1.0f + r00 - r11 - r22, r10 + r01,              r20 + r02,              r21 - r12 },
        { r10 + r01,              1.0f - r00 + r11 - r22, r21 + r12,              r02 - r20 },
        { r20 + r02,              r21 + r12,              1.0f - r00 - r11 + r22, r10 - r01 },
        { r21 - r12,              r02 - r20,              r10 - r01,              1.0f + t  }
    };
    float dec[4] = { r00, r11, r22, t };
    int ch = 0;
    float best = dec[0];
#pragma unroll
    for (int j = 1; j < 4; ++j) {
        if (dec[j] > best) { best = dec[j]; ch = j; }   // first-max tie-break like jnp.argmax
    }
    float qx = cand[ch][0], qy = cand[ch][1], qz = cand[ch][2], qw = cand[ch][3];
    float qn = sqrtf(qx * qx + qy * qy + qz * qz + qw * qw);
    float inv = 1.0f / qn;
    // xyzw -> wxyz
    quat_wxyz = make_float4(qw * inv, qx * inv, qy * inv, qz * inv);
}

__global__ __launch_bounds__(256)
void face_kernel(const float* __restrict__ verts, const int* __restrict__ faces,
                 float4* __restrict__ fd, int nf)
{
    int f = blockIdx.x * 256 + threadIdx.x;
    if (f >= nf) return;
    F3 a0, a1, a2, ctr; float fs; float4 quat;
    face_geom(verts, faces, f, a0, a1, a2, ctr, fs, quat);
    fd[5 * f + 0] = make_float4(a0.x, a0.y, a0.z, ctr.x);
    fd[5 * f + 1] = make_float4(a1.x, a1.y, a1.z, ctr.y);
    fd[5 * f + 2] = make_float4(a2.x, a2.y, a2.z, ctr.z);
    fd[5 * f + 3] = quat;
    fd[5 * f + 4] = make_float4(fs, 0.0f, 0.0f, 0.0f);
}

__device__ __forceinline__ void gauss_body(
    int i,
    float4 f0, float4 f1, float4 f2, float4 fq, float fs,
    const float* __restrict__ xyz, const float* __restrict__ opa,
    const float* __restrict__ scl, const float4* __restrict__ rot_raw,
    const float* __restrict__ fdc, float* __restrict__ out)
{
    float x = xyz[3 * i + 0], y = xyz[3 * i + 1], z = xyz[3 * i + 2];
    // g = (R @ xyz) * fs + center ; R cols = a0(f0) a1(f1) a2(f2), center in .w
    float gx = (f0.x * x + f1.x * y + f2.x * z) * fs + f0.w;
    float gy = (f0.y * x + f1.y * y + f2.y * z) * fs + f1.w;
    float gz = (f0.z * x + f1.z * y + f2.z * z) * fs + f2.w;

    float s0 = expf(scl[3 * i + 0]) * fs;
    float s1 = expf(scl[3 * i + 1]) * fs;
    float s2 = expf(scl[3 * i + 2]) * fs;

    float o = 1.0f / (1.0f + expf(-opa[i]));

    float4 r = rot_raw[i];  // wxyz raw
    float rn = sqrtf(r.x * r.x + r.y * r.y + r.z * r.z + r.w * r.w) + 1e-12f;
    float rinv = 1.0f / rn;
    float rw = r.x * rinv, rx = r.y * rinv, ry = r.z * rinv, rz = r.w * rinv;

    // fq (wxyz) is unit; the reference's /(norm+1e-12) rounds to /1.0f in f32.
    float pw = fq.x, px = fq.y, py = fq.z, pz = fq.w;
    // Hamilton product p (xyzw view) * q (xyzw view):
    float vx = pw * rx + rw * px + (py * rz - pz * ry);
    float vy = pw * ry + rw * py + (pz * rx - px * rz);
    float vz = pw * rz + rw * pz + (px * ry - py * rx);
    float vw = pw * rw - (px * rx + py * ry + pz * rz);
    float qn = sqrtf(vx * vx + vy * vy + vz * vz + vw * vw);
    float qinv = 1.0f / qn;

    float c0 = fminf(fmaxf((0.5f + 0.282f * fdc[3 * i + 0]) * 255.0f, 0.0f), 255.0f);
    float c1 = fminf(fmaxf((0.5f + 0.282f * fdc[3 * i + 1]) * 255.0f, 0.0f), 255.0f);
    float c2 = fminf(fmaxf((0.5f + 0.282f * fdc[3 * i + 2]) * 255.0f, 0.0f), 255.0f);
    float c3 = fminf(fmaxf(o * 255.0f, 0.0f), 255.0f);

    float* po = out + (size_t)i * 14;
    po[0]  = gx;        po[1]  = gy;        po[2]  = gz;
    po[3]  = s0;        po[4]  = s1;        po[5]  = s2;
    po[6]  = c0;        po[7]  = c1;        po[8]  = c2;        po[9] = c3;
    po[10] = vw * qinv; po[11] = vx * qinv; po[12] = vy * qinv; po[13] = vz * qinv;
}

__global__ __launch_bounds__(256)
void gauss_main(const float* __restrict__ xyz, const float* __restrict__ opa,
                const float* __restrict__ scl, const float4* __restrict__ rot_raw,
                const float* __restrict__ fdc, const int* __restrict__ binding,
                const float4* __restrict__ face, float* __restrict__ out, int n)
{
    int i = blockIdx.x * 256 + threadIdx.x;
    if (i >= n) return;
    int b = binding[i];
    float4 f0 = face[5 * b + 0];
    float4 f1 = face[5 * b + 1];
    float4 f2 = face[5 * b + 2];
    float4 fq = face[5 * b + 3];
    float fs  = face[5 * b + 4].x;
    gauss_body(i, f0, f1, f2, fq, fs, xyz, opa, scl, rot_raw, fdc, out);
}

// Fallback if ws_size is too small for the face table: recompute face geometry
// per gaussian (verts/faces stay L2-resident; extra VALU only).
__global__ __launch_bounds__(256)
void gauss_fused(const float* __restrict__ verts, const int* __restrict__ faces,
                 const float* __restrict__ xyz, const float* __restrict__ opa,
                 const float* __restrict__ scl, const float4* __restrict__ rot_raw,
                 const float* __restrict__ fdc, const int* __restrict__ binding,
                 float* __restrict__ out, int n)
{
    int i = blockIdx.x * 256 + threadIdx.x;
    if (i >= n) return;
    int b = binding[i];
    F3 a0, a1, a2, ctr; float fs; float4 quat;
    face_geom(verts, faces, b, a0, a1, a2, ctr, fs, quat);
    float4 f0 = make_float4(a0.x, a0.y, a0.z, ctr.x);
    float4 f1 = make_float4(a1.x, a1.y, a1.z, ctr.y);
    float4 f2 = make_float4(a2.x, a2.y, a2.z, ctr.z);
    gauss_body(i, f0, f1, f2, quat, fs, xyz, opa, scl, rot_raw, fdc, out);
}

extern "C" void kernel_launch(void* const* d_in, const int* in_sizes, int n_in,
                              void* d_out, int out_size, void* d_ws, size_t ws_size,
                              hipStream_t stream)
{
    const float* verts   = (const float*)d_in[0];
    const float* xyz     = (const float*)d_in[1];
    const float* opa     = (const float*)d_in[2];
    const float* scl     = (const float*)d_in[3];
    const float* rot     = (const float*)d_in[4];
    const float* fdc     = (const float*)d_in[5];
    // d_in[6] = features_rest : UNUSED by the reference output — never read.
    const int*   faces   = (const int*)d_in[7];
    const int*   binding = (const int*)d_in[8];

    int n      = in_sizes[8];        // N_GAUSS
    int nfaces = in_sizes[7] / 3;    // N_FACES
    float* out = (float*)d_out;

    size_t need = (size_t)nfaces * 5 * sizeof(float4);
    int gblocks = (n + 255) / 256;

    if (ws_size >= need) {
        float4* face = (float4*)d_ws;
        hipLaunchKernelGGL(face_kernel, dim3((nfaces + 255) / 256), dim3(256), 0, stream,
                           verts, faces, face, nfaces);
        hipLaunchKernelGGL(gauss_main, dim3(gblocks), dim3(256), 0, stream,
                           xyz, opa, scl, (const float4*)rot, fdc, binding, face, out, n);
    } else {
        hipLaunchKernelGGL(gauss_fused, dim3(gblocks), dim3(256), 0, stream,
                           verts, faces, xyz, opa, scl, (const float4*)rot, fdc, binding, out, n);
    }
}